// Round 2
// baseline (61.413 us; speedup 1.0000x reference)
//
#include <hip/hip_runtime.h>
#include <math.h>

// Problem dims (fixed by the reference)
#define M_COMP  8
#define DIN     1024   // input size = DK = DV
#define HDV     4096   // H * DV
#define HID     1024
#define DTOT    8192   // HID * M
#define NV_ROWS 32768  // M_COMP * HDV
#define V_BLOCKS 8192  // NV_ROWS / 4 waves-per-block

typedef float f32x4 __attribute__((ext_vector_type(4)));

__device__ __forceinline__ float wave_reduce_sum(float v) {
    #pragma unroll
    for (int off = 32; off > 0; off >>= 1)
        v += __shfl_down(v, off, 64);
    return v;
}

// ---------------------------------------------------------------------------
// Fused big kernel: two INDEPENDENT streaming halves share one grid.
//   v-half (8192 blocks): v[row] = x[m,:]·Wv[row,:] + bv[row]
//   u-half (32*npart blocks): u-partials over Wo:
//       upart[jc][m*HDV+i] = sum_{j in chunk jc} c[m,j] * Wo[m,j,i],
//       c[d] = W[d]^2 * Wout[d]
// Interleave: every `stride`-th block is a u-block so both matrices stream
// concurrently (no serial drain between the 134 MB passes).
// ---------------------------------------------------------------------------
__global__ __launch_bounds__(256) void k_fused(
    const float* __restrict__ x, const float* __restrict__ Wv,
    const float* __restrict__ bv, const float* __restrict__ Wo,
    const float* __restrict__ W, const float* __restrict__ Wout,
    float* __restrict__ v_out, float* __restrict__ upart,
    int npart, int stride, int J)
{
    const int bid  = blockIdx.x;
    const int bq   = bid / stride;
    const int lane = threadIdx.x & 63;
    const int wib  = threadIdx.x >> 6;

    if ((bid % stride) != 0) {
        // ---- v half: one wave per Wv row (4 KB) ----
        const int vb  = bid - bq - 1;          // 0 .. V_BLOCKS-1
        const int row = vb * 4 + wib;          // 0 .. NV_ROWS-1
        const int m   = row >> 12;
        const float* __restrict__ xr = x + m * DIN;
        const float* __restrict__ wr = Wv + (size_t)row * DIN;
        float acc = 0.f;
        #pragma unroll
        for (int it = 0; it < DIN / 256; ++it) {
            const int d = it * 256 + lane * 4;
            const f32x4 w4 = __builtin_nontemporal_load(
                reinterpret_cast<const f32x4*>(wr + d));
            const f32x4 x4 = *reinterpret_cast<const f32x4*>(xr + d);
            acc += w4.x * x4.x + w4.y * x4.y + w4.z * x4.z + w4.w * x4.w;
        }
        acc = wave_reduce_sum(acc);
        if (lane == 0) v_out[row] = acc + bv[row];
    } else {
        // ---- u half: wave owns (m, i-chunk of 256, j-chunk of J rows) ----
        const int w     = bq * 4 + wib;        // 0 .. 128*npart-1
        const int per_m = 16 * npart;
        const int m     = w / per_m;
        const int rem   = w % per_m;
        const int ic    = rem / npart;
        const int jc    = rem % npart;
        const int d0    = m * HID + jc * J;
        const float* __restrict__ base =
            Wo + (size_t)d0 * HDV + ic * 256 + lane * 4;
        f32x4 acc = {0.f, 0.f, 0.f, 0.f};
        #pragma unroll 4
        for (int j = 0; j < J; ++j) {
            const float wj = W[d0 + j];
            const float c  = wj * wj * Wout[d0 + j];
            const f32x4 w4 = __builtin_nontemporal_load(
                reinterpret_cast<const f32x4*>(base + (size_t)j * HDV));
            acc += w4 * c;
        }
        *reinterpret_cast<f32x4*>(
            upart + (size_t)jc * NV_ROWS + m * HDV + ic * 256 + lane * 4) = acc;
    }
}

// ---------------------------------------------------------------------------
// Combine: partial[b] = sum over this block's slice of
//   v[e]*u[e]  (u = sum of npart partials)  +  (bo[d]-K0[d])*c[d]
// 128 blocks x 256 threads; deterministic fixed-tree reduction.
// ---------------------------------------------------------------------------
__global__ __launch_bounds__(256) void k_combine(
    const float* __restrict__ v, const float* __restrict__ upart, int npart,
    const float* __restrict__ bo, const float* __restrict__ K0,
    const float* __restrict__ W, const float* __restrict__ Wout,
    float* __restrict__ partials)
{
    const int b = blockIdx.x, t = threadIdx.x;
    const int e = b * 256 + t;                 // 0 .. NV_ROWS-1
    float u = 0.f;
    for (int p = 0; p < npart; ++p) u += upart[(size_t)p * NV_ROWS + e];
    float val = u * v[e];
    if (t < 64) {
        const int d = b * 64 + t;              // 0 .. DTOT-1
        const float w = W[d];
        val += (bo[d] - K0[d]) * w * w * Wout[d];
    }
    val = wave_reduce_sum(val);
    __shared__ float s[4];
    if ((t & 63) == 0) s[t >> 6] = val;
    __syncthreads();
    if (t == 0) partials[b] = s[0] + s[1] + s[2] + s[3];
}

__global__ __launch_bounds__(128) void k_final2(
    const float* __restrict__ partials, const float* __restrict__ bout,
    float* __restrict__ out)
{
    const int t = threadIdx.x;
    float val = partials[t];                   // 128 partials, one per thread
    val = wave_reduce_sum(val);
    __shared__ float s[2];
    if ((t & 63) == 0) s[t >> 6] = val;
    __syncthreads();
    if (t == 0) out[0] = 1.f / (1.f + expf(-(s[0] + s[1] + bout[0])));
}

// ---------------------------------------------------------------------------
// Fallback (round-1 structure) in case ws is too small for u-partials.
// ---------------------------------------------------------------------------
__global__ __launch_bounds__(256) void k_v_matvec(
    const float* __restrict__ x, const float* __restrict__ Wv,
    const float* __restrict__ bv, float* __restrict__ v_out)
{
    const int gwave = (int)((blockIdx.x * blockDim.x + threadIdx.x) >> 6);
    const int lane  = threadIdx.x & 63;
    if (gwave >= NV_ROWS) return;
    const int m = gwave >> 12;
    const float* __restrict__ xr = x + m * DIN;
    const float* __restrict__ wr = Wv + (size_t)gwave * DIN;
    float acc = 0.f;
    #pragma unroll
    for (int it = 0; it < DIN / 256; ++it) {
        const int d = it * 256 + lane * 4;
        const float4 w4 = *reinterpret_cast<const float4*>(wr + d);
        const float4 x4 = *reinterpret_cast<const float4*>(xr + d);
        acc += w4.x * x4.x + w4.y * x4.y + w4.z * x4.z + w4.w * x4.w;
    }
    acc = wave_reduce_sum(acc);
    if (lane == 0) v_out[gwave] = acc + bv[gwave];
}

__global__ __launch_bounds__(256) void k_out_matvec(
    const float* __restrict__ v, const float* __restrict__ Wo,
    const float* __restrict__ bo, const float* __restrict__ K0,
    const float* __restrict__ W, const float* __restrict__ Wout,
    float* __restrict__ t_out)
{
    const int d    = (int)((blockIdx.x * blockDim.x + threadIdx.x) >> 6);
    const int lane = threadIdx.x & 63;
    if (d >= DTOT) return;
    const int m = d >> 10;
    const float* __restrict__ vr = v + m * HDV;
    const float* __restrict__ wr = Wo + (size_t)d * HDV;
    float acc = 0.f;
    #pragma unroll
    for (int it = 0; it < HDV / 256; ++it) {
        const int i = it * 256 + lane * 4;
        const float4 w4 = *reinterpret_cast<const float4*>(wr + i);
        const float4 v4 = *reinterpret_cast<const float4*>(vr + i);
        acc += w4.x * v4.x + w4.y * v4.y + w4.z * v4.z + w4.w * v4.w;
    }
    acc = wave_reduce_sum(acc);
    if (lane == 0) {
        const float outd = acc + bo[d];
        const float w    = W[d];
        t_out[d] = (outd - K0[d]) * w * w * Wout[d];
    }
}

__global__ __launch_bounds__(256) void k_final(
    const float* __restrict__ t, const float* __restrict__ bout,
    float* __restrict__ out)
{
    __shared__ float sred[4];
    const int tid = threadIdx.x;
    float acc = 0.f;
    #pragma unroll
    for (int k = 0; k < DTOT / 256; ++k)
        acc += t[tid + k * 256];
    acc = wave_reduce_sum(acc);
    if ((tid & 63) == 0) sred[tid >> 6] = acc;
    __syncthreads();
    if (tid == 0) {
        const float total = sred[0] + sred[1] + sred[2] + sred[3] + bout[0];
        out[0] = 1.f / (1.f + expf(-total));
    }
}

extern "C" void kernel_launch(void* const* d_in, const int* in_sizes, int n_in,
                              void* d_out, int out_size, void* d_ws, size_t ws_size,
                              hipStream_t stream) {
    // setup_inputs order:
    // 0:x 1:Wq 2:bq 3:Wk 4:bk 5:Wv 6:bv 7:Wo 8:bo 9:K 10:W 11:Wout 12:bout
    const float* x    = (const float*)d_in[0];
    const float* Wv   = (const float*)d_in[5];
    const float* bv   = (const float*)d_in[6];
    const float* Wo   = (const float*)d_in[7];
    const float* bo   = (const float*)d_in[8];
    const float* K    = (const float*)d_in[9];   // only row 0 needed (argmin(cumsum(>=0))==0)
    const float* W    = (const float*)d_in[10];
    const float* Wout = (const float*)d_in[11];
    const float* bout = (const float*)d_in[12];
    float* out = (float*)d_out;

    float* v_ws = (float*)d_ws;

    // pick the largest u-partial count that fits the workspace
    const size_t base_need = ((size_t)NV_ROWS + 128) * sizeof(float);
    int npart = 0;
    const int cands[5] = {32, 16, 8, 4, 2};
    for (int i = 0; i < 5; ++i) {
        if (ws_size >= base_need + (size_t)cands[i] * NV_ROWS * sizeof(float)) {
            npart = cands[i];
            break;
        }
    }

    if (npart) {
        float* upart    = v_ws + NV_ROWS;
        float* partials = upart + (size_t)npart * NV_ROWS;
        const int stride = 256 / npart + 1;           // exact interleave
        const int total  = V_BLOCKS + 32 * npart;     // = 32*npart * stride
        const int J      = HID / npart;
        k_fused<<<total, 256, 0, stream>>>(x, Wv, bv, Wo, W, Wout,
                                           v_ws, upart, npart, stride, J);
        k_combine<<<128, 256, 0, stream>>>(v_ws, upart, npart, bo, K, W, Wout,
                                           partials);
        k_final2<<<1, 128, 0, stream>>>(partials, bout, out);
    } else {
        // round-1 fallback (fits in 160 KB of ws)
        float* t_ws = v_ws + NV_ROWS;
        k_v_matvec<<<NV_ROWS / 4, 256, 0, stream>>>(x, Wv, bv, v_ws);
        k_out_matvec<<<DTOT / 4, 256, 0, stream>>>(v_ws, Wo, bo, K, W, Wout, t_ws);
        k_final<<<1, 256, 0, stream>>>(t_ws, bout, out);
    }
}

// Round 3
// 48.640 us; speedup vs baseline: 1.2626x; 1.2626x over previous
//
#include <hip/hip_runtime.h>
#include <math.h>

// Problem dims (fixed by the reference)
#define M_COMP  8
#define DIN     1024   // input size = DK = DV
#define HDV     4096   // H * DV
#define HID     1024
#define DTOT    8192   // HID * M
#define NV_ROWS 32768  // M_COMP * HDV

typedef float f32x4 __attribute__((ext_vector_type(4)));

__device__ __forceinline__ float wave_reduce_sum(float v) {
    #pragma unroll
    for (int off = 32; off > 0; off >>= 1)
        v += __shfl_down(v, off, 64);
    return v;
}

// ---------------------------------------------------------------------------
// Kernel 1: v[row] = x[m,:]·Wv[row,:] + bv[row].
// One wave per 4 CONSECUTIVE rows (16 KB contiguous stream per wave).
// x segment is register-cached (16 floats/lane) and reused for all 4 rows.
// 8192 waves -> 2048 blocks -> 32 waves/CU (full occupancy).
// ---------------------------------------------------------------------------
__global__ __launch_bounds__(256) void k_v4(
    const float* __restrict__ x, const float* __restrict__ Wv,
    const float* __restrict__ bv, float* __restrict__ v_out)
{
    const int wave = (int)((blockIdx.x * blockDim.x + threadIdx.x) >> 6);
    const int lane = threadIdx.x & 63;
    const int row0 = wave * 4;                     // 0..NV_ROWS-4
    const int m    = row0 >> 12;                   // 4096 rows per m
    const float* __restrict__ xr = x + m * DIN;
    f32x4 xv[4];
    #pragma unroll
    for (int it = 0; it < 4; ++it)
        xv[it] = *reinterpret_cast<const f32x4*>(xr + it * 256 + lane * 4);

    const float* __restrict__ wr = Wv + (size_t)row0 * DIN;
    float acc[4] = {0.f, 0.f, 0.f, 0.f};
    #pragma unroll
    for (int r = 0; r < 4; ++r) {
        #pragma unroll
        for (int it = 0; it < 4; ++it) {
            const f32x4 w4 = *reinterpret_cast<const f32x4*>(
                wr + (size_t)r * DIN + it * 256 + lane * 4);
            acc[r] += w4.x * xv[it].x + w4.y * xv[it].y +
                      w4.z * xv[it].z + w4.w * xv[it].w;
        }
    }
    #pragma unroll
    for (int r = 0; r < 4; ++r) {
        const float s = wave_reduce_sum(acc[r]);
        if (lane == 0) v_out[row0 + r] = s + bv[row0 + r];
    }
}

// ---------------------------------------------------------------------------
// Kernel 2: per-wave partial of sum_d t[d], where
//   t[d] = (v[m,:]·Wo[d,:] + bo[d] - K0[d]) * W[d]^2 * Wout[d].
// One wave per 2 CONSECUTIVE d-rows (32 KB contiguous stream); each v4 load
// is shared by both rows (v re-read traffic halved, stays L1-hot).
// 4096 waves -> 1024 blocks -> 16 waves/CU.
// ---------------------------------------------------------------------------
__global__ __launch_bounds__(256) void k_o2(
    const float* __restrict__ v, const float* __restrict__ Wo,
    const float* __restrict__ bo, const float* __restrict__ K0,
    const float* __restrict__ W, const float* __restrict__ Wout,
    float* __restrict__ partials)
{
    const int wave = (int)((blockIdx.x * blockDim.x + threadIdx.x) >> 6);
    const int lane = threadIdx.x & 63;
    const int d0   = wave * 2;                     // 0..DTOT-2
    const int m    = d0 >> 10;                     // 1024 rows per m
    const float* __restrict__ vr = v + m * HDV;
    const float* __restrict__ wr = Wo + (size_t)d0 * HDV;
    float acc0 = 0.f, acc1 = 0.f;
    #pragma unroll
    for (int it = 0; it < 16; ++it) {
        const int i = it * 256 + lane * 4;
        const f32x4 v4 = *reinterpret_cast<const f32x4*>(vr + i);
        const f32x4 a4 = *reinterpret_cast<const f32x4*>(wr + i);
        const f32x4 b4 = *reinterpret_cast<const f32x4*>(wr + HDV + i);
        acc0 += a4.x * v4.x + a4.y * v4.y + a4.z * v4.z + a4.w * v4.w;
        acc1 += b4.x * v4.x + b4.y * v4.y + b4.z * v4.z + b4.w * v4.w;
    }
    acc0 = wave_reduce_sum(acc0);
    acc1 = wave_reduce_sum(acc1);
    if (lane == 0) {
        const float w0 = W[d0],     c0 = w0 * w0 * Wout[d0];
        const float w1 = W[d0 + 1], c1 = w1 * w1 * Wout[d0 + 1];
        partials[wave] = (acc0 + bo[d0]     - K0[d0])     * c0 +
                         (acc1 + bo[d0 + 1] - K0[d0 + 1]) * c1;
    }
}

// ---------------------------------------------------------------------------
// Kernel 3: reduce 4096 partials + bout, sigmoid. Single block, fixed tree.
// ---------------------------------------------------------------------------
__global__ __launch_bounds__(256) void k_fin(
    const float* __restrict__ partials, const float* __restrict__ bout,
    float* __restrict__ out)
{
    const int t = threadIdx.x;
    float acc = 0.f;
    #pragma unroll
    for (int k = 0; k < 4096 / 256; ++k)
        acc += partials[t + k * 256];
    acc = wave_reduce_sum(acc);
    __shared__ float s[4];
    if ((t & 63) == 0) s[t >> 6] = acc;
    __syncthreads();
    if (t == 0)
        out[0] = 1.f / (1.f + expf(-(s[0] + s[1] + s[2] + s[3] + bout[0])));
}

extern "C" void kernel_launch(void* const* d_in, const int* in_sizes, int n_in,
                              void* d_out, int out_size, void* d_ws, size_t ws_size,
                              hipStream_t stream) {
    // setup_inputs order:
    // 0:x 1:Wq 2:bq 3:Wk 4:bk 5:Wv 6:bv 7:Wo 8:bo 9:K 10:W 11:Wout 12:bout
    const float* x    = (const float*)d_in[0];
    const float* Wv   = (const float*)d_in[5];
    const float* bv   = (const float*)d_in[6];
    const float* Wo   = (const float*)d_in[7];
    const float* bo   = (const float*)d_in[8];
    const float* K    = (const float*)d_in[9];   // only row 0 needed: argmin(cumsum(>=0)) == 0
    const float* W    = (const float*)d_in[10];
    const float* Wout = (const float*)d_in[11];
    const float* bout = (const float*)d_in[12];
    float* out = (float*)d_out;

    // workspace layout: v (32768 f32) | partials (4096 f32)
    float* v_ws = (float*)d_ws;
    float* p_ws = v_ws + NV_ROWS;

    // Kernel 1: 32768 rows / 4 per wave / 4 waves per block = 2048 blocks
    k_v4<<<NV_ROWS / 16, 256, 0, stream>>>(x, Wv, bv, v_ws);
    // Kernel 2: 8192 rows / 2 per wave / 4 waves per block = 1024 blocks
    k_o2<<<DTOT / 8, 256, 0, stream>>>(v_ws, Wo, bo, K, W, Wout, p_ws);
    // Kernel 3: single block
    k_fin<<<1, 256, 0, stream>>>(p_ws, bout, out);
}